// Round 5
// baseline (1333.419 us; speedup 1.0000x reference)
//
#include <hip/hip_runtime.h>
#include <stdint.h>
#include <math.h>

// SparseDiffAttn: o_cache = o_dense - o_sparse(top-896 keys per 192-query group)
// B=1, H=24, N=3072, D=128, BM=192, QG=16, TK=896. fp32 in/out.
// kS: pre-split K into 3 bf16 tiers (hi/mid/lo, RNE).
// kAB loop1: Z rowsums, f64 accumulate (3-tier z: Z row-noise feeds top-k compare).
// kAB loop2: o_dense + per-chunk colsums (2-tier z: only needs +-1.6e-5 resolution).
// kC: two-phase top-k — fp32 threshold, then f64-exact recompute of boundary
//     candidates (|c-V|<=MARG) -> ranking matches f64 reference except at
//     true gaps < ~1e-10 (P~1e-3). jax tie semantics via (c64 desc, idx asc).
// kD: o_S,rho over selected set (2-tier; self-normalizing), out -= o_S/rho.

#define H 24
#define N 3072
#define DH 128
#define SCALE 0.08838834764831845f
#define TK 896
#define MARG 1.6e-5f
#define MAXC 96

typedef __attribute__((ext_vector_type(8))) short short8;   // 8 bf16
typedef __attribute__((ext_vector_type(4))) float f32x4;
typedef __attribute__((address_space(1))) unsigned char GAS;
typedef __attribute__((address_space(3))) unsigned char LAS;
#define GLD16(g, l) __builtin_amdgcn_global_load_lds((GAS*)(g), (LAS*)(l), 16, 0, 0)

__device__ __forceinline__ uint32_t bf_rne(float x){
  uint32_t u = __float_as_uint(x);
  return (u + 0x7FFFu + ((u >> 16) & 1u)) >> 16;
}

__device__ __forceinline__ f32x4 f4zero(){ f32x4 z = {0.f,0.f,0.f,0.f}; return z; }

// 2-way RNE split: q = h + l (+ r, |r| <= 2^-18 |q|)
__device__ __forceinline__ void split8_2(const float* f, uint4& h4, uint4& l4){
  uint32_t hw[4], lw[4];
#pragma unroll
  for (int i = 0; i < 4; i++){
    float a = f[2*i], b = f[2*i+1];
    uint32_t ha = bf_rne(a), hb = bf_rne(b);
    float ra = a - __uint_as_float(ha << 16);
    float rb = b - __uint_as_float(hb << 16);
    hw[i] = ha | (hb << 16);
    lw[i] = bf_rne(ra) | (bf_rne(rb) << 16);
  }
  h4.x = hw[0]; h4.y = hw[1]; h4.z = hw[2]; h4.w = hw[3];
  l4.x = lw[0]; l4.y = lw[1]; l4.z = lw[2]; l4.w = lw[3];
}

// 3-way RNE split: q = h + m + l (+ r, |r| <= 2^-27 |q|)
__device__ __forceinline__ void split8_3(const float* f, uint4& h4, uint4& m4, uint4& l4){
  uint32_t hw[4], mw[4], lw[4];
#pragma unroll
  for (int i = 0; i < 4; i++){
    float a = f[2*i], b = f[2*i+1];
    uint32_t ha = bf_rne(a), hb = bf_rne(b);
    float ra = a - __uint_as_float(ha << 16);
    float rb = b - __uint_as_float(hb << 16);
    uint32_t ma = bf_rne(ra), mb = bf_rne(rb);
    float la = ra - __uint_as_float(ma << 16);
    float lb = rb - __uint_as_float(mb << 16);
    hw[i] = ha | (hb << 16);
    mw[i] = ma | (mb << 16);
    lw[i] = bf_rne(la) | (bf_rne(lb) << 16);
  }
  h4.x = hw[0]; h4.y = hw[1]; h4.z = hw[2]; h4.w = hw[3];
  m4.x = mw[0]; m4.y = mw[1]; m4.z = mw[2]; m4.w = mw[3];
  l4.x = lw[0]; l4.y = lw[1]; l4.z = lw[2]; l4.w = lw[3];
}

__device__ __forceinline__ short8 as_s8(const uint4 u){
  union { uint4 u4; short8 s; } t; t.u4 = u; return t.s;
}

// 1152 blocks = 8 XCD * (3 heads * 48 chunks)
__device__ __forceinline__ void mapHC(int bid, int& h, int& ch){
  int x = bid & 7;
  int i = bid >> 3;
  h = x + 8 * (i / 48);
  ch = i % 48;
}

__device__ __forceinline__ void load_qfrags2(const float* qhead, int R, int w, int lane,
                                             uint4* qh, uint4* ql){
  int row = R + w*16 + (lane & 15);
  const float* qp = qhead + (size_t)row * DH;
#pragma unroll
  for (int s = 0; s < 4; s++){
    int d0 = s*32 + (lane >> 4)*8;
    float4 a = *(const float4*)(qp + d0);
    float4 b = *(const float4*)(qp + d0 + 4);
    float f[8] = {a.x*SCALE, a.y*SCALE, a.z*SCALE, a.w*SCALE,
                  b.x*SCALE, b.y*SCALE, b.z*SCALE, b.w*SCALE};
    split8_2(f, qh[s], ql[s]);
  }
}

__device__ __forceinline__ void load_qfrags3(const float* qhead, int R, int w, int lane,
                                             uint4* qh, uint4* qm, uint4* ql){
  int row = R + w*16 + (lane & 15);
  const float* qp = qhead + (size_t)row * DH;
#pragma unroll
  for (int s = 0; s < 4; s++){
    int d0 = s*32 + (lane >> 4)*8;
    float4 a = *(const float4*)(qp + d0);
    float4 b = *(const float4*)(qp + d0 + 4);
    float f[8] = {a.x*SCALE, a.y*SCALE, a.z*SCALE, a.w*SCALE,
                  b.x*SCALE, b.y*SCALE, b.z*SCALE, b.w*SCALE};
    split8_3(f, qh[s], qm[s], ql[s]);
  }
}

// in-situ: stage one K row-slice into granule-XOR-swizzled 2-tier tiles
__device__ __forceinline__ void stage_k2(const float* kp, char* khi, char* klo,
                                         int jst, int dblk){
  float4 a = *(const float4*)(kp);
  float4 b = *(const float4*)(kp + 4);
  float4 c = *(const float4*)(kp + 8);
  float4 d = *(const float4*)(kp + 12);
  float f0[8] = {a.x,a.y,a.z,a.w,b.x,b.y,b.z,b.w};
  float f1[8] = {c.x,c.y,c.z,c.w,d.x,d.y,d.z,d.w};
  uint4 h4, l4;
  int base = jst*256 + dblk*32;
  int sw = (jst & 7) << 4;
  split8_2(f0, h4, l4);
  *(uint4*)(khi + (base ^ sw)) = h4;
  *(uint4*)(klo + (base ^ sw)) = l4;
  split8_2(f1, h4, l4);
  *(uint4*)(khi + ((base + 16) ^ sw)) = h4;
  *(uint4*)(klo + ((base + 16) ^ sw)) = l4;
}

__device__ __forceinline__ void stage_k3(const float* kp, char* khi, char* kmi, char* klo,
                                         int jst, int dblk){
  float4 a = *(const float4*)(kp);
  float4 b = *(const float4*)(kp + 4);
  float4 c = *(const float4*)(kp + 8);
  float4 d = *(const float4*)(kp + 12);
  float f0[8] = {a.x,a.y,a.z,a.w,b.x,b.y,b.z,b.w};
  float f1[8] = {c.x,c.y,c.z,c.w,d.x,d.y,d.z,d.w};
  uint4 h4, m4, l4;
  int base = jst*256 + dblk*32;
  int sw = (jst & 7) << 4;
  split8_3(f0, h4, m4, l4);
  *(uint4*)(khi + (base ^ sw)) = h4;
  *(uint4*)(kmi + (base ^ sw)) = m4;
  *(uint4*)(klo + (base ^ sw)) = l4;
  split8_3(f1, h4, m4, l4);
  *(uint4*)(khi + ((base + 16) ^ sw)) = h4;
  *(uint4*)(kmi + ((base + 16) ^ sw)) = m4;
  *(uint4*)(klo + ((base + 16) ^ sw)) = l4;
}

// stage V key-pair transposed: vts[d][key] bf16 pairs, pitch 80B, row-bit3 XOR
__device__ __forceinline__ void stage_v2(const float* vp0, const float* vp1,
                                         char* vts, int jv2, int dv8){
  float4 a0 = *(const float4*)(vp0);
  float4 b0 = *(const float4*)(vp0 + 4);
  float4 a1 = *(const float4*)(vp1);
  float4 b1 = *(const float4*)(vp1 + 4);
  float f0[8] = {a0.x,a0.y,a0.z,a0.w,b0.x,b0.y,b0.z,b0.w};
  float f1[8] = {a1.x,a1.y,a1.z,a1.w,b1.x,b1.y,b1.z,b1.w};
#pragma unroll
  for (int i = 0; i < 8; i++){
    uint32_t wrd = bf_rne(f0[i]) | (bf_rne(f1[i]) << 16);
    int r = dv8 + i;
    int off = (r*80 + jv2*2) ^ (((r >> 3) & 1) << 4);
    *(uint32_t*)(vts + off) = wrd;
  }
}

// z[16x32] via 2-tier (qh+ql)(kh+kl): 4 MFMA
__device__ __forceinline__ void zcompute4(const char* khi, const char* klo,
                                          const uint4* qh, const uint4* ql,
                                          int lane, f32x4* zac){
  zac[0] = f4zero(); zac[1] = f4zero();
#pragma unroll
  for (int s = 0; s < 4; s++){
    short8 qa = as_s8(qh[s]);
    short8 qb = as_s8(ql[s]);
#pragma unroll
    for (int ct = 0; ct < 2; ct++){
      int key = ct*16 + (lane & 15);
      int off = (key*256 + (s*32 + (lane >> 4)*8)*2) ^ ((key & 7) << 4);
      short8 kh = *(const short8*)(khi + off);
      short8 kl = *(const short8*)(klo + off);
      zac[ct] = __builtin_amdgcn_mfma_f32_16x16x32_bf16(qb, kl, zac[ct], 0, 0, 0);
      zac[ct] = __builtin_amdgcn_mfma_f32_16x16x32_bf16(qb, kh, zac[ct], 0, 0, 0);
      zac[ct] = __builtin_amdgcn_mfma_f32_16x16x32_bf16(qa, kl, zac[ct], 0, 0, 0);
      zac[ct] = __builtin_amdgcn_mfma_f32_16x16x32_bf16(qa, kh, zac[ct], 0, 0, 0);
    }
  }
}

// z[16x32] via 3-way {mm,hl,lh,hm,mh,hh}: 6 MFMA (Z loop)
__device__ __forceinline__ void zcompute6(const char* khi, const char* kmi, const char* klo,
                                          const uint4* qh, const uint4* qm, const uint4* ql,
                                          int lane, f32x4* zac){
  zac[0] = f4zero(); zac[1] = f4zero();
#pragma unroll
  for (int s = 0; s < 4; s++){
    short8 qa = as_s8(qh[s]);
    short8 qb = as_s8(qm[s]);
    short8 qc = as_s8(ql[s]);
#pragma unroll
    for (int ct = 0; ct < 2; ct++){
      int key = ct*16 + (lane & 15);
      int off = (key*256 + (s*32 + (lane >> 4)*8)*2) ^ ((key & 7) << 4);
      short8 kh = *(const short8*)(khi + off);
      short8 km = *(const short8*)(kmi + off);
      short8 kl = *(const short8*)(klo + off);
      zac[ct] = __builtin_amdgcn_mfma_f32_16x16x32_bf16(qb, km, zac[ct], 0, 0, 0);
      zac[ct] = __builtin_amdgcn_mfma_f32_16x16x32_bf16(qa, kl, zac[ct], 0, 0, 0);
      zac[ct] = __builtin_amdgcn_mfma_f32_16x16x32_bf16(qc, kh, zac[ct], 0, 0, 0);
      zac[ct] = __builtin_amdgcn_mfma_f32_16x16x32_bf16(qa, km, zac[ct], 0, 0, 0);
      zac[ct] = __builtin_amdgcn_mfma_f32_16x16x32_bf16(qb, kh, zac[ct], 0, 0, 0);
      zac[ct] = __builtin_amdgcn_mfma_f32_16x16x32_bf16(qa, kh, zac[ct], 0, 0, 0);
    }
  }
}

// P->bf16 LDS (swizzled), then PV MFMA accumulate
__device__ __forceinline__ void pv_step(const float pn[2][4], char* pw, const char* vts,
                                        f32x4* oac, int l15, int l4){
#pragma unroll
  for (int ct = 0; ct < 2; ct++)
#pragma unroll
    for (int r = 0; r < 4; r++){
      int row = l4*4 + r;
      int off = (row*80 + (ct*16 + l15)*2) ^ (((row >> 3) & 1) << 4);
      *(unsigned short*)(pw + off) = (unsigned short)bf_rne(pn[ct][r]);
    }
  int offA = (l15*80 + l4*16) ^ (((l15 >> 3) & 1) << 4);
  short8 ap = *(const short8*)(pw + offA);
#pragma unroll
  for (int vt = 0; vt < 8; vt++){
    int vrow = vt*16 + l15;
    int offB = (vrow*80 + l4*16) ^ (((vrow >> 3) & 1) << 4);
    short8 vb = *(const short8*)(vts + offB);
    oac[vt] = __builtin_amdgcn_mfma_f32_16x16x32_bf16(ap, vb, oac[vt], 0, 0, 0);
  }
}

// ---------------- kernel S: pre-split K into 3 bf16 tiers ----------------
__global__ __launch_bounds__(256) void kS(const float* __restrict__ kg,
                                          unsigned short* __restrict__ khig,
                                          unsigned short* __restrict__ kmig,
                                          unsigned short* __restrict__ klog){
  size_t idx = ((size_t)blockIdx.x*256 + threadIdx.x)*8;
  float4 a = *(const float4*)(kg + idx);
  float4 b = *(const float4*)(kg + idx + 4);
  float f[8] = {a.x,a.y,a.z,a.w,b.x,b.y,b.z,b.w};
  uint4 h4, m4, l4;
  split8_3(f, h4, m4, l4);
  *(uint4*)(khig + idx) = h4;
  *(uint4*)(kmig + idx) = m4;
  *(uint4*)(klog + idx) = l4;
}

// ------- kernel AB: loop1 rowsums Z (f64); loop2 o_dense + colsum partials -------
template<int DMA>
__global__ __launch_bounds__(256, 4) void kAB(const float* __restrict__ qg,
                                              const float* __restrict__ kg,
                                              const float* __restrict__ vg,
                                              const unsigned short* __restrict__ khig,
                                              const unsigned short* __restrict__ kmig,
                                              const unsigned short* __restrict__ klog,
                                              double* __restrict__ Zg,
                                              float* __restrict__ cpart,
                                              float* __restrict__ outg){
  __shared__ alignas(16) char khi[8192];
  __shared__ alignas(16) char kmi[8192];
  __shared__ alignas(16) char klo[8192];
  __shared__ alignas(16) char vts[10240];
  __shared__ alignas(16) char pls[4][1280];
  __shared__ float colbuf[4][32];
  int h, ch; mapHC(blockIdx.x, h, ch);
  const int tid = threadIdx.x, w = tid >> 6, lane = tid & 63;
  const int l15 = lane & 15, l4 = lane >> 4;
  const int R = ch * 64;
  const float* qhead = qg + (size_t)h*N*DH;
  const float* khead = kg + (size_t)h*N*DH;
  const float* vhead = vg + (size_t)h*N*DH;
  uint4 qh[4], qm[4], ql[4];
  load_qfrags3(qhead, R, w, lane, qh, qm, ql);

  size_t b0 = 0, b1 = 0;
  if (DMA){
    int g0 = w*128 + lane, g1 = g0 + 64;
    int k0 = g0 >> 4, sl0 = (g0 & 15) ^ (k0 & 7);
    int k1 = g1 >> 4, sl1 = (g1 & 15) ^ (k1 & 7);
    b0 = ((size_t)h*N + k0)*DH + sl0*8;
    b1 = ((size_t)h*N + k1)*DH + sl1*8;
  }
  const int wofs = w*2048;
  const int jst = tid >> 3, dblk = tid & 7;

  // ---- loop 1: Z rowsums, 3-tier z, f64 accumulate ----
  double zs[4] = {0.0,0.0,0.0,0.0};
  for (int kt = 0; kt < 96; kt++){
    if (DMA){
      size_t st = (size_t)kt*32*DH;
      GLD16(khig + b0 + st, khi + wofs);  GLD16(khig + b1 + st, khi + wofs + 1024);
      GLD16(kmig + b0 + st, kmi + wofs);  GLD16(kmig + b1 + st, kmi + wofs + 1024);
      GLD16(klog + b0 + st, klo + wofs);  GLD16(klog + b1 + st, klo + wofs + 1024);
    } else {
      stage_k3(khead + (size_t)(kt*32 + jst)*DH + dblk*16, khi, kmi, klo, jst, dblk);
    }
    __syncthreads();
    f32x4 zac[2];
    zcompute6(khi, kmi, klo, qh, qm, ql, lane, zac);
#pragma unroll
    for (int ct = 0; ct < 2; ct++)
#pragma unroll
      for (int r = 0; r < 4; r++)
        zs[r] += (double)__expf(zac[ct][r]);
    __syncthreads();
  }
#pragma unroll
  for (int m = 1; m < 16; m <<= 1)
#pragma unroll
    for (int r = 0; r < 4; r++)
      zs[r] += __shfl_xor(zs[r], m);
  float rz[4];
#pragma unroll
  for (int r = 0; r < 4; r++) rz[r] = (float)(1.0 / zs[r]);
  if (l15 == 0){
#pragma unroll
    for (int r = 0; r < 4; r++)
      Zg[h*N + R + w*16 + l4*4 + r] = zs[r];
  }

  // ---- loop 2: o_dense + colsums (2-tier hi+mid, 4 MFMA) ----
  f32x4 oac[8];
#pragma unroll
  for (int i = 0; i < 8; i++) oac[i] = f4zero();
  const int jv2 = (tid & 15)*2, dv8 = (tid >> 4)*8;
  float* cp = cpart + (size_t)(h*48 + ch) * 3072;
  for (int kt = 0; kt < 96; kt++){
    if (kt > 0 && tid < 32)
      cp[(kt-1)*32 + tid] = colbuf[0][tid] + colbuf[1][tid] + colbuf[2][tid] + colbuf[3][tid];
    if (DMA){
      size_t st = (size_t)kt*32*DH;
      GLD16(khig + b0 + st, khi + wofs);  GLD16(khig + b1 + st, khi + wofs + 1024);
      GLD16(kmig + b0 + st, kmi + wofs);  GLD16(kmig + b1 + st, kmi + wofs + 1024);
    } else {
      stage_k2(khead + (size_t)(kt*32 + jst)*DH + dblk*16, khi, kmi, jst, dblk);
    }
    stage_v2(vhead + (size_t)(kt*32 + jv2)*DH + dv8,
             vhead + (size_t)(kt*32 + jv2 + 1)*DH + dv8, vts, jv2, dv8);
    __syncthreads();
    f32x4 zac[2];
    zcompute4(khi, kmi, qh, qm, lane, zac);
    float pn[2][4];
#pragma unroll
    for (int ct = 0; ct < 2; ct++)
#pragma unroll
      for (int r = 0; r < 4; r++)
        pn[ct][r] = __expf(zac[ct][r]) * rz[r];
#pragma unroll
    for (int ct = 0; ct < 2; ct++){
      float cs = pn[ct][0] + pn[ct][1] + pn[ct][2] + pn[ct][3];
      cs += __shfl_xor(cs, 16);
      cs += __shfl_xor(cs, 32);
      if (lane < 16) colbuf[w][ct*16 + lane] = cs;
    }
    pv_step(pn, pls[w], vts, oac, l15, l4);
    __syncthreads();
  }
  if (tid < 32)
    cp[95*32 + tid] = colbuf[0][tid] + colbuf[1][tid] + colbuf[2][tid] + colbuf[3][tid];
#pragma unroll
  for (int vt = 0; vt < 8; vt++)
#pragma unroll
    for (int r = 0; r < 4; r++)
      outg[((size_t)h*N + R + w*16 + l4*4 + r)*DH + vt*16 + l15] = oac[vt][r];
}

// ------ kernel C: two-phase top-896: fp32 threshold + f64 boundary refine ------
__global__ __launch_bounds__(256, 2) void kC(const float* __restrict__ cpart,
                                             const double* __restrict__ Zd,
                                             const float* __restrict__ qg,
                                             const float* __restrict__ kg,
                                             int* __restrict__ selg){
  __shared__ float cu[3072];
  __shared__ int red[4];
  __shared__ int runS;
  __shared__ int cidx[MAXC];
  __shared__ double cval[MAXC];
  __shared__ double rbuf[256];
  const int gid = blockIdx.x;           // h*16+g
  const int h = gid >> 4, g = gid & 15;
  const int tid = threadIdx.x, w = tid >> 6, lane = tid & 63;
  const float* p0 = cpart + (size_t)(h*48 + g*3) * 3072;
  const float* p1 = p0 + 3072;
  const float* p2 = p0 + 6144;
  for (int i = tid; i < 3072; i += 256)
    cu[i] = p0[i] + p1[i] + p2[i];
  __syncthreads();
  // phase 1: threshold V on float bits (positive -> bit-monotone)
  uint32_t lo = 0u, hi = 0xFFFFFFFFu;
  for (int it = 0; it < 32; it++){
    bool active = (lo < hi);
    uint32_t mid = (uint32_t)(((uint64_t)lo + (uint64_t)hi + 1ull) >> 1);
    int c = 0;
    if (active){
      for (int i = tid; i < 3072; i += 256)
        c += (__float_as_uint(cu[i]) >= mid) ? 1 : 0;
#pragma unroll
      for (int m = 1; m < 64; m <<= 1) c += __shfl_xor(c, m);
    }
    if (lane == 0) red[w] = c;
    __syncthreads();
    int tot = red[0] + red[1] + red[2] + red[3];
    __syncthreads();
    if (active){ if (tot >= TK) lo = mid; else hi = mid - 1; }
  }
  const float Vf = __uint_as_float(lo);
  const float thr_hi = Vf + MARG;
  const float thr_lo = Vf - MARG;
  // n_in = count(cu > thr_hi)
  {
    int c = 0;
    for (int i = tid; i < 3072; i += 256) c += (cu[i] > thr_hi) ? 1 : 0;
#pragma unroll
    for (int m = 1; m < 64; m <<= 1) c += __shfl_xor(c, m);
    if (lane == 0) red[w] = c;
  }
  __syncthreads();
  const int n_in = red[0] + red[1] + red[2] + red[3];
  const int need = TK - n_in;
  int* sb = selg + (size_t)gid * TK;
  // sweep 1: safe-in keys -> sb[0..n_in)
  if (tid == 0) runS = 0;
  __syncthreads();
  for (int ck = 0; ck < 12; ck++){
    int j = ck*256 + tid;
    bool f = (cu[j] > thr_hi);
    unsigned long long bal = __ballot(f);
    int wpre = __popcll(bal & ((1ull << lane) - 1ull));
    int wtot = __popcll(bal);
    if (lane == 0) red[w] = wtot;
    __syncthreads();
    int woff = 0;
    for (int x = 0; x < w; x++) woff += red[x];
    int base = runS;
    if (f) sb[base + woff + wpre] = j;
    __syncthreads();
    if (tid == 0) runS = base + red[0] + red[1] + red[2] + red[3];
    __syncthreads();
  }
  // sweep 2: candidates (thr_lo <= cu <= thr_hi) -> cidx[]
  if (tid == 0) runS = 0;
  __syncthreads();
  for (int ck = 0; ck < 12; ck++){
    int j = ck*256 + tid;
    bool f = (!(cu[j] > thr_hi)) && (cu[j] >= thr_lo);
    unsigned long long bal = __ballot(f);
    int wpre = __popcll(bal & ((1ull << lane) - 1ull));
    int wtot = __popcll(bal);
    if (lane == 0) red[w] = wtot;
    __syncthreads();
    int woff = 0;
    for (int x = 0; x < w; x++) woff += red[x];
    int base = runS;
    int pos = base + woff + wpre;
    if (f && pos < MAXC) cidx[pos] = j;
    __syncthreads();
    if (tid == 0) runS = base + red[0] + red[1] + red[2] + red[3];
    __syncthreads();
  }
  int ccnt = runS < MAXC ? runS : MAXC;
  __syncthreads();
  // phase 2: f64 colsum for each candidate
  const int row = g*192 + (tid < 192 ? tid : 0);
  const float* qp = qg + ((size_t)h*N + row)*DH;
  const double zinv_d = (tid < 192) ? 1.0 / 1.0 : 0.0; (void)zinv_d;
  const double Zrow = Zd[h*N + row];
  for (int c = 0; c < ccnt; c++){
    double t = 0.0;
    if (tid < 192){
      const float* kp = kg + ((size_t)h*N + cidx[c])*DH;
      double a0 = 0.0, a1 = 0.0, a2 = 0.0, a3 = 0.0;
#pragma unroll 4
      for (int d = 0; d < DH; d += 4){
        a0 = fma((double)qp[d],   (double)kp[d],   a0);
        a1 = fma((double)qp[d+1], (double)kp[d+1], a1);
        a2 = fma((double)qp[d+2], (double)kp[d+2], a2);
        a3 = fma((double)qp[d+3], (double)kp[d+3], a3);
      }
      double z = ((a0 + a1) + (a2 + a3)) * 0.08838834764831845;
      t = exp(z) / Zrow;
    }
    rbuf[tid] = t;
    __syncthreads();
#pragma unroll
    for (int s = 128; s > 0; s >>= 1){
      if (tid < s) rbuf[tid] += rbuf[tid + s];
      __syncthreads();
    }
    if (tid == 0) cval[c] = rbuf[0];
    __syncthreads();
  }
  // rank candidates by (c64 desc, idx asc); fill sb[n_in .. TK)
  if (tid < ccnt){
    double my = cval[tid];
    int myi = cidx[tid];
    int rank = 0;
    for (int u = 0; u < ccnt; u++){
      double cu_ = cval[u];
      if (cu_ > my || (cu_ == my && cidx[u] < myi)) rank++;
    }
    if (rank < need) sb[n_in + rank] = myi;
  }
}

// ------- kernel D: o_S, rho over selected keys; out -= o_S/rho (in place) -------
template<int DMA>
__global__ __launch_bounds__(256, 4) void kD(const float* __restrict__ qg,
                                             const float* __restrict__ kg,
                                             const float* __restrict__ vg,
                                             const double* __restrict__ Zg,
                                             const int* __restrict__ selg,
                                             const unsigned short* __restrict__ khig,
                                             const unsigned short* __restrict__ kmig,
                                             float* __restrict__ outg){
  __shared__ alignas(16) char khi[8192];
  __shared__ alignas(16) char klo[8192];
  __shared__ alignas(16) char vts[10240];
  __shared__ alignas(16) char pls[4][1280];
  __shared__ int sell[TK];
  int h, ch; mapHC(blockIdx.x, h, ch);
  const int tid = threadIdx.x, w = tid >> 6, lane = tid & 63;
  const int l15 = lane & 15, l4 = lane >> 4;
  const int R = ch * 64;
  const int g = ch / 3;
  const float* qhead = qg + (size_t)h*N*DH;
  const float* khead = kg + (size_t)h*N*DH;
  const float* vhead = vg + (size_t)h*N*DH;
  const int* sb = selg + (size_t)(h*16 + g) * TK;
  for (int i = tid; i < TK; i += 256) sell[i] = sb[i];
  uint4 qh[4], ql[4];
  load_qfrags2(qhead, R, w, lane, qh, ql);
  float rz[4];
#pragma unroll
  for (int r = 0; r < 4; r++)
    rz[r] = (float)(1.0 / Zg[h*N + R + w*16 + l4*4 + r]);
  f32x4 oac[8];
#pragma unroll
  for (int i = 0; i < 8; i++) oac[i] = f4zero();
  float rh[4] = {0.f,0.f,0.f,0.f};

  int p0g = 0, p1g = 0, sl0 = 0, sl1 = 0;
  if (DMA){
    int g0 = w*128 + lane, g1 = g0 + 64;
    p0g = g0 >> 4; sl0 = (g0 & 15) ^ (p0g & 7);
    p1g = g1 >> 4; sl1 = (g1 & 15) ^ (p1g & 7);
  }
  const int wofs = w*2048;
  const int jst = tid >> 3, dblk = tid & 7;
  const int jv2 = (tid & 15)*2, dv8 = (tid >> 4)*8;
  __syncthreads();
  for (int st = 0; st < 28; st++){
    if (DMA){
      size_t b0 = ((size_t)h*N + sell[st*32 + p0g])*DH + sl0*8;
      size_t b1 = ((size_t)h*N + sell[st*32 + p1g])*DH + sl1*8;
      GLD16(khig + b0, khi + wofs);  GLD16(khig + b1, khi + wofs + 1024);
      GLD16(kmig + b0, klo + wofs);  GLD16(kmig + b1, klo + wofs + 1024);
    } else {
      int key = sell[st*32 + jst];
      stage_k2(khead + (size_t)key*DH + dblk*16, khi, klo, jst, dblk);
    }
    {
      int ka_ = sell[st*32 + jv2], kb_ = sell[st*32 + jv2 + 1];
      stage_v2(vhead + (size_t)ka_*DH + dv8, vhead + (size_t)kb_*DH + dv8,
               vts, jv2, dv8);
    }
    __syncthreads();
    f32x4 zac[2];
    zcompute4(khi, klo, qh, ql, lane, zac);
    float pn[2][4];
#pragma unroll
    for (int ct = 0; ct < 2; ct++)
#pragma unroll
      for (int r = 0; r < 4; r++){
        pn[ct][r] = __expf(zac[ct][r]) * rz[r];
        rh[r] += pn[ct][r];
      }
    pv_step(pn, pls[w], vts, oac, l15, l4);
    __syncthreads();
  }
#pragma unroll
  for (int m = 1; m < 16; m <<= 1)
#pragma unroll
    for (int r = 0; r < 4; r++)
      rh[r] += __shfl_xor(rh[r], m);
  float ri[4];
#pragma unroll
  for (int r = 0; r < 4; r++) ri[r] = 1.0f / rh[r];
#pragma unroll
  for (int vt = 0; vt < 8; vt++)
#pragma unroll
    for (int r = 0; r < 4; r++){
      size_t idx = ((size_t)h*N + R + w*16 + l4*4 + r)*DH + vt*16 + l15;
      outg[idx] = outg[idx] - oac[vt][r]*ri[r];
    }
}

extern "C" void kernel_launch(void* const* d_in, const int* in_sizes, int n_in,
                              void* d_out, int out_size, void* d_ws, size_t ws_size,
                              hipStream_t stream){
  (void)in_sizes; (void)n_in; (void)out_size;
  const float* q = (const float*)d_in[0];
  const float* k = (const float*)d_in[1];
  const float* v = (const float*)d_in[2];
  float* out = (float*)d_out;
  const size_t KELEMS = (size_t)H*N*DH;            // 9,437,184
  const size_t KBYTES = KELEMS*2;                  // 18,874,368
  const size_t ZB = (size_t)H*N*8;                 // 589,824 (f64)
  const size_t CPB = (size_t)1152*3072*4;          // 14,155,776
  const size_t SELB = (size_t)384*TK*4;            // 1,376,256
  const bool dma = ws_size >= 3*KBYTES + ZB + CPB + SELB;   // ~72.8 MB
  char* wsb = (char*)d_ws;
  unsigned short *khig = nullptr, *kmig = nullptr, *klog = nullptr;
  double* Z; float* cpart; int* sel;
  if (dma){
    khig = (unsigned short*)wsb;
    kmig = (unsigned short*)(wsb + KBYTES);
    klog = (unsigned short*)(wsb + 2*KBYTES);
    Z = (double*)(wsb + 3*KBYTES);
    cpart = (float*)(wsb + 3*KBYTES + ZB);
    sel = (int*)(wsb + 3*KBYTES + ZB + CPB);
  } else {
    Z = (double*)wsb;
    cpart = (float*)(wsb + ZB);
    sel = (int*)(wsb + ZB + CPB);
  }
  if (dma){
    kS<<<dim3(4608), dim3(256), 0, stream>>>(k, khig, kmig, klog);
    kAB<1><<<dim3(1152), dim3(256), 0, stream>>>(q, k, v, khig, kmig, klog, Z, cpart, out);
    kC<<<dim3(384), dim3(256), 0, stream>>>(cpart, Z, q, k, sel);
    kD<1><<<dim3(1152), dim3(256), 0, stream>>>(q, k, v, Z, sel, khig, kmig, out);
  } else {
    kAB<0><<<dim3(1152), dim3(256), 0, stream>>>(q, k, v, khig, kmig, klog, Z, cpart, out);
    kC<<<dim3(384), dim3(256), 0, stream>>>(cpart, Z, q, k, sel);
    kD<0><<<dim3(1152), dim3(256), 0, stream>>>(q, k, v, Z, sel, khig, kmig, out);
  }
}

// Round 6
// 851.557 us; speedup vs baseline: 1.5659x; 1.5659x over previous
//
#include <hip/hip_runtime.h>
#include <stdint.h>
#include <math.h>

// SparseDiffAttn: o_cache = o_dense - o_sparse(top-896 keys per 192-query group)
// B=1, H=24, N=3072, D=128, BM=192, QG=16, TK=896. fp32 in/out.
// kS: pre-split K into 2 bf16 tiers (hi/lo, RNE).
// kAB loop1: Z rowsums (2-tier 3-MFMA {hh,hl,lh}, f64 acc; eps_Z ~1e-7, budget 2.5e-6).
// kAB loop2: o_dense + per-chunk colsums (same 3-MFMA; colsum err ~2e-8, budget 8e-6).
// kC: UNCHANGED from round-5 PASS — two-phase top-k, f64 boundary refine.
// kD: o_S,rho over selected set (3-MFMA; self-normalizing), out -= o_S/rho.
// Pipeline: K double-buffered w/ GLD16 prefetch of t+1 during compute(t);
// V reg-staged (T14: load early, ds_write after mid-barrier). 2 barriers/iter.

#define H 24
#define N 3072
#define DH 128
#define SCALE 0.08838834764831845f
#define TK 896
#define MARG 1.6e-5f
#define MAXC 96

typedef __attribute__((ext_vector_type(8))) short short8;   // 8 bf16
typedef __attribute__((ext_vector_type(4))) float f32x4;
typedef __attribute__((address_space(1))) unsigned char GAS;
typedef __attribute__((address_space(3))) unsigned char LAS;
#define GLD16(g, l) __builtin_amdgcn_global_load_lds((GAS*)(g), (LAS*)(l), 16, 0, 0)

__device__ __forceinline__ uint32_t bf_rne(float x){
  uint32_t u = __float_as_uint(x);
  return (u + 0x7FFFu + ((u >> 16) & 1u)) >> 16;
}

__device__ __forceinline__ f32x4 f4zero(){ f32x4 z = {0.f,0.f,0.f,0.f}; return z; }

// 2-way RNE split: q = h + l (+ r, |r| <= 2^-18 |q|)
__device__ __forceinline__ void split8_2(const float* f, uint4& h4, uint4& l4){
  uint32_t hw[4], lw[4];
#pragma unroll
  for (int i = 0; i < 4; i++){
    float a = f[2*i], b = f[2*i+1];
    uint32_t ha = bf_rne(a), hb = bf_rne(b);
    float ra = a - __uint_as_float(ha << 16);
    float rb = b - __uint_as_float(hb << 16);
    hw[i] = ha | (hb << 16);
    lw[i] = bf_rne(ra) | (bf_rne(rb) << 16);
  }
  h4.x = hw[0]; h4.y = hw[1]; h4.z = hw[2]; h4.w = hw[3];
  l4.x = lw[0]; l4.y = lw[1]; l4.z = lw[2]; l4.w = lw[3];
}

__device__ __forceinline__ short8 as_s8(const uint4 u){
  union { uint4 u4; short8 s; } t; t.u4 = u; return t.s;
}

// 1152 blocks = 8 XCD * (3 heads * 48 chunks)
__device__ __forceinline__ void mapHC(int bid, int& h, int& ch){
  int x = bid & 7;
  int i = bid >> 3;
  h = x + 8 * (i / 48);
  ch = i % 48;
}

__device__ __forceinline__ void load_qfrags2(const float* qhead, int R, int w, int lane,
                                             uint4* qh, uint4* ql){
  int row = R + w*16 + (lane & 15);
  const float* qp = qhead + (size_t)row * DH;
#pragma unroll
  for (int s = 0; s < 4; s++){
    int d0 = s*32 + (lane >> 4)*8;
    float4 a = *(const float4*)(qp + d0);
    float4 b = *(const float4*)(qp + d0 + 4);
    float f[8] = {a.x*SCALE, a.y*SCALE, a.z*SCALE, a.w*SCALE,
                  b.x*SCALE, b.y*SCALE, b.z*SCALE, b.w*SCALE};
    split8_2(f, qh[s], ql[s]);
  }
}

// in-situ fallback: K row-slice f32 regs (issue early), split+write (late)
__device__ __forceinline__ void ldK16(const float* kp, float4* r){
  r[0] = *(const float4*)(kp);
  r[1] = *(const float4*)(kp + 4);
  r[2] = *(const float4*)(kp + 8);
  r[3] = *(const float4*)(kp + 12);
}
__device__ __forceinline__ void wrK16(const float4* r, char* khi, char* klo,
                                      int jst, int dblk){
  float f0[8] = {r[0].x,r[0].y,r[0].z,r[0].w,r[1].x,r[1].y,r[1].z,r[1].w};
  float f1[8] = {r[2].x,r[2].y,r[2].z,r[2].w,r[3].x,r[3].y,r[3].z,r[3].w};
  uint4 h4, l4;
  int base = jst*256 + dblk*32;
  int sw = (jst & 7) << 4;
  split8_2(f0, h4, l4);
  *(uint4*)(khi + (base ^ sw)) = h4;
  *(uint4*)(klo + (base ^ sw)) = l4;
  split8_2(f1, h4, l4);
  *(uint4*)(khi + ((base + 16) ^ sw)) = h4;
  *(uint4*)(klo + ((base + 16) ^ sw)) = l4;
}

// V reg-staging (T14): load two key rows early, convert+write late
struct V16 { float4 a0, b0, a1, b1; };
__device__ __forceinline__ V16 load_v(const float* vp0, const float* vp1){
  V16 v;
  v.a0 = *(const float4*)(vp0);
  v.b0 = *(const float4*)(vp0 + 4);
  v.a1 = *(const float4*)(vp1);
  v.b1 = *(const float4*)(vp1 + 4);
  return v;
}
__device__ __forceinline__ void write_v(const V16& v, char* vts, int jv2, int dv8){
  float f0[8] = {v.a0.x,v.a0.y,v.a0.z,v.a0.w,v.b0.x,v.b0.y,v.b0.z,v.b0.w};
  float f1[8] = {v.a1.x,v.a1.y,v.a1.z,v.a1.w,v.b1.x,v.b1.y,v.b1.z,v.b1.w};
#pragma unroll
  for (int i = 0; i < 8; i++){
    uint32_t wrd = bf_rne(f0[i]) | (bf_rne(f1[i]) << 16);
    int r = dv8 + i;
    int off = (r*80 + jv2*2) ^ (((r >> 3) & 1) << 4);
    *(uint32_t*)(vts + off) = wrd;
  }
}

// z[16x32] via 2-tier {hl, lh, hh}: 3 MFMA, eps_z ~6e-6 (small terms first)
__device__ __forceinline__ void zcompute3(const char* khi, const char* klo,
                                          const uint4* qh, const uint4* ql,
                                          int lane, f32x4* zac){
  zac[0] = f4zero(); zac[1] = f4zero();
#pragma unroll
  for (int s = 0; s < 4; s++){
    short8 qa = as_s8(qh[s]);
    short8 qb = as_s8(ql[s]);
#pragma unroll
    for (int ct = 0; ct < 2; ct++){
      int key = ct*16 + (lane & 15);
      int off = (key*256 + (s*32 + (lane >> 4)*8)*2) ^ ((key & 7) << 4);
      short8 kh = *(const short8*)(khi + off);
      short8 kl = *(const short8*)(klo + off);
      zac[ct] = __builtin_amdgcn_mfma_f32_16x16x32_bf16(qa, kl, zac[ct], 0, 0, 0);
      zac[ct] = __builtin_amdgcn_mfma_f32_16x16x32_bf16(qb, kh, zac[ct], 0, 0, 0);
      zac[ct] = __builtin_amdgcn_mfma_f32_16x16x32_bf16(qa, kh, zac[ct], 0, 0, 0);
    }
  }
}

// P->bf16 LDS (swizzled), then PV MFMA accumulate
__device__ __forceinline__ void pv_step(const float pn[2][4], char* pw, const char* vts,
                                        f32x4* oac, int l15, int l4){
#pragma unroll
  for (int ct = 0; ct < 2; ct++)
#pragma unroll
    for (int r = 0; r < 4; r++){
      int row = l4*4 + r;
      int off = (row*80 + (ct*16 + l15)*2) ^ (((row >> 3) & 1) << 4);
      *(unsigned short*)(pw + off) = (unsigned short)bf_rne(pn[ct][r]);
    }
  int offA = (l15*80 + l4*16) ^ (((l15 >> 3) & 1) << 4);
  short8 ap = *(const short8*)(pw + offA);
#pragma unroll
  for (int vt = 0; vt < 8; vt++){
    int vrow = vt*16 + l15;
    int offB = (vrow*80 + l4*16) ^ (((vrow >> 3) & 1) << 4);
    short8 vb = *(const short8*)(vts + offB);
    oac[vt] = __builtin_amdgcn_mfma_f32_16x16x32_bf16(ap, vb, oac[vt], 0, 0, 0);
  }
}

// ---------------- kernel S: pre-split K into 2 bf16 tiers ----------------
__global__ __launch_bounds__(256) void kS(const float* __restrict__ kg,
                                          unsigned short* __restrict__ khig,
                                          unsigned short* __restrict__ klog){
  size_t idx = ((size_t)blockIdx.x*256 + threadIdx.x)*8;
  float4 a = *(const float4*)(kg + idx);
  float4 b = *(const float4*)(kg + idx + 4);
  float f[8] = {a.x,a.y,a.z,a.w,b.x,b.y,b.z,b.w};
  uint4 h4, l4;
  split8_2(f, h4, l4);
  *(uint4*)(khig + idx) = h4;
  *(uint4*)(klog + idx) = l4;
}

// ------- kernel AB: loop1 rowsums Z (f64); loop2 o_dense + colsum partials -------
template<int DMA>
__global__ __launch_bounds__(256, 3) void kAB(const float* __restrict__ qg,
                                              const float* __restrict__ kg,
                                              const float* __restrict__ vg,
                                              const unsigned short* __restrict__ khig,
                                              const unsigned short* __restrict__ klog,
                                              double* __restrict__ Zg,
                                              float* __restrict__ cpart,
                                              float* __restrict__ outg){
  __shared__ alignas(16) char khi[2][8192];
  __shared__ alignas(16) char klo[2][8192];
  __shared__ alignas(16) char vts[10240];
  __shared__ alignas(16) char pls[4][1280];
  __shared__ float colbuf[2][4][32];
  int h, ch; mapHC(blockIdx.x, h, ch);
  const int tid = threadIdx.x, w = tid >> 6, lane = tid & 63;
  const int l15 = lane & 15, l4 = lane >> 4;
  const int R = ch * 64;
  const float* qhead = qg + (size_t)h*N*DH;
  const float* khead = kg + (size_t)h*N*DH;
  const float* vhead = vg + (size_t)h*N*DH;
  uint4 qh[4], ql[4];
  load_qfrags2(qhead, R, w, lane, qh, ql);

  size_t b0 = 0, b1 = 0;
  if (DMA){
    int g0 = w*128 + lane, g1 = g0 + 64;
    int k0 = g0 >> 4, sl0 = (g0 & 15) ^ (k0 & 7);
    int k1 = g1 >> 4, sl1 = (g1 & 15) ^ (k1 & 7);
    b0 = ((size_t)h*N + k0)*DH + sl0*8;
    b1 = ((size_t)h*N + k1)*DH + sl1*8;
  }
  const int wofs = w*2048;
  const int jst = tid >> 3, dblk = tid & 7;
  const int jv2 = (tid & 15)*2, dv8 = (tid >> 4)*8;

  // ---- loop 1: Z rowsums ----
  if (DMA){
    GLD16(khig + b0, khi[0] + wofs);  GLD16(khig + b1, khi[0] + wofs + 1024);
    GLD16(klog + b0, klo[0] + wofs);  GLD16(klog + b1, klo[0] + wofs + 1024);
  } else {
    float4 k0r[4];
    ldK16(khead + (size_t)jst*DH + dblk*16, k0r);
    wrK16(k0r, khi[0], klo[0], jst, dblk);
  }
  __syncthreads();
  double zs[4] = {0.0,0.0,0.0,0.0};
  float4 kr[4];
  for (int kt = 0; kt < 96; kt++){
    int cur = kt & 1;
    if (kt < 95){
      if (DMA){
        size_t st = (size_t)(kt+1)*32*DH;
        GLD16(khig + b0 + st, khi[cur^1] + wofs);  GLD16(khig + b1 + st, khi[cur^1] + wofs + 1024);
        GLD16(klog + b0 + st, klo[cur^1] + wofs);  GLD16(klog + b1 + st, klo[cur^1] + wofs + 1024);
      } else {
        ldK16(khead + (size_t)((kt+1)*32 + jst)*DH + dblk*16, kr);
      }
    }
    f32x4 zac[2];
    zcompute3(khi[cur], klo[cur], qh, ql, lane, zac);
#pragma unroll
    for (int ct = 0; ct < 2; ct++)
#pragma unroll
      for (int r = 0; r < 4; r++)
        zs[r] += (double)__expf(zac[ct][r]);
    if (!DMA && kt < 95) wrK16(kr, khi[cur^1], klo[cur^1], jst, dblk);
    __syncthreads();
  }
#pragma unroll
  for (int m = 1; m < 16; m <<= 1)
#pragma unroll
    for (int r = 0; r < 4; r++)
      zs[r] += __shfl_xor(zs[r], m);
  float rz[4];
#pragma unroll
  for (int r = 0; r < 4; r++) rz[r] = (float)(1.0 / zs[r]);
  if (l15 == 0){
#pragma unroll
    for (int r = 0; r < 4; r++)
      Zg[h*N + R + w*16 + l4*4 + r] = zs[r];
  }

  // ---- loop 2: o_dense + colsum partials ----
  if (DMA){
    GLD16(khig + b0, khi[0] + wofs);  GLD16(khig + b1, khi[0] + wofs + 1024);
    GLD16(klog + b0, klo[0] + wofs);  GLD16(klog + b1, klo[0] + wofs + 1024);
  } else {
    float4 k0r[4];
    ldK16(khead + (size_t)jst*DH + dblk*16, k0r);
    wrK16(k0r, khi[0], klo[0], jst, dblk);
  }
  {
    V16 v0 = load_v(vhead + (size_t)jv2*DH + dv8, vhead + (size_t)(jv2+1)*DH + dv8);
    write_v(v0, vts, jv2, dv8);
  }
  __syncthreads();
  f32x4 oac[8];
#pragma unroll
  for (int i = 0; i < 8; i++) oac[i] = f4zero();
  float* cp = cpart + (size_t)(h*48 + ch) * 3072;
  V16 vr;
  for (int kt = 0; kt < 96; kt++){
    int cur = kt & 1;
    if (kt > 0 && tid < 32)
      cp[(kt-1)*32 + tid] = colbuf[cur^1][0][tid] + colbuf[cur^1][1][tid]
                          + colbuf[cur^1][2][tid] + colbuf[cur^1][3][tid];
    if (kt < 95){
      if (DMA){
        size_t st = (size_t)(kt+1)*32*DH;
        GLD16(khig + b0 + st, khi[cur^1] + wofs);  GLD16(khig + b1 + st, khi[cur^1] + wofs + 1024);
        GLD16(klog + b0 + st, klo[cur^1] + wofs);  GLD16(klog + b1 + st, klo[cur^1] + wofs + 1024);
      } else {
        ldK16(khead + (size_t)((kt+1)*32 + jst)*DH + dblk*16, kr);
      }
      vr = load_v(vhead + (size_t)((kt+1)*32 + jv2)*DH + dv8,
                  vhead + (size_t)((kt+1)*32 + jv2 + 1)*DH + dv8);
    }
    f32x4 zac[2];
    zcompute3(khi[cur], klo[cur], qh, ql, lane, zac);
    float pn[2][4];
#pragma unroll
    for (int ct = 0; ct < 2; ct++)
#pragma unroll
      for (int r = 0; r < 4; r++)
        pn[ct][r] = __expf(zac[ct][r]) * rz[r];
#pragma unroll
    for (int ct = 0; ct < 2; ct++){
      float cs = pn[ct][0] + pn[ct][1] + pn[ct][2] + pn[ct][3];
      cs += __shfl_xor(cs, 16);
      cs += __shfl_xor(cs, 32);
      if (lane < 16) colbuf[cur][w][ct*16 + lane] = cs;
    }
    pv_step(pn, pls[w], vts, oac, l15, l4);
    __syncthreads();                       // barrier1: vts readers done
    if (kt < 95){
      write_v(vr, vts, jv2, dv8);
      if (!DMA) wrK16(kr, khi[cur^1], klo[cur^1], jst, dblk);
    }
    __syncthreads();                       // barrier2: next tile ready
  }
  if (tid < 32)
    cp[95*32 + tid] = colbuf[1][0][tid] + colbuf[1][1][tid]
                    + colbuf[1][2][tid] + colbuf[1][3][tid];
#pragma unroll
  for (int vt = 0; vt < 8; vt++)
#pragma unroll
    for (int r = 0; r < 4; r++)
      outg[((size_t)h*N + R + w*16 + l4*4 + r)*DH + vt*16 + l15] = oac[vt][r];
}

// ------ kernel C: two-phase top-896 (UNCHANGED from round-5 PASS) ------
__global__ __launch_bounds__(256, 2) void kC(const float* __restrict__ cpart,
                                             const double* __restrict__ Zd,
                                             const float* __restrict__ qg,
                                             const float* __restrict__ kg,
                                             int* __restrict__ selg){
  __shared__ float cu[3072];
  __shared__ int red[4];
  __shared__ int runS;
  __shared__ int cidx[MAXC];
  __shared__ double cval[MAXC];
  __shared__ double rbuf[256];
  const int gid = blockIdx.x;           // h*16+g
  const int h = gid >> 4, g = gid & 15;
  const int tid = threadIdx.x, w = tid >> 6, lane = tid & 63;
  const float* p0 = cpart + (size_t)(h*48 + g*3) * 3072;
  const float* p1 = p0 + 3072;
  const float* p2 = p0 + 6144;
  for (int i = tid; i < 3072; i += 256)
    cu[i] = p0[i] + p1[i] + p2[i];
  __syncthreads();
  uint32_t lo = 0u, hi = 0xFFFFFFFFu;
  for (int it = 0; it < 32; it++){
    bool active = (lo < hi);
    uint32_t mid = (uint32_t)(((uint64_t)lo + (uint64_t)hi + 1ull) >> 1);
    int c = 0;
    if (active){
      for (int i = tid; i < 3072; i += 256)
        c += (__float_as_uint(cu[i]) >= mid) ? 1 : 0;
#pragma unroll
      for (int m = 1; m < 64; m <<= 1) c += __shfl_xor(c, m);
    }
    if (lane == 0) red[w] = c;
    __syncthreads();
    int tot = red[0] + red[1] + red[2] + red[3];
    __syncthreads();
    if (active){ if (tot >= TK) lo = mid; else hi = mid - 1; }
  }
  const float Vf = __uint_as_float(lo);
  const float thr_hi = Vf + MARG;
  const float thr_lo = Vf - MARG;
  {
    int c = 0;
    for (int i = tid; i < 3072; i += 256) c += (cu[i] > thr_hi) ? 1 : 0;
#pragma unroll
    for (int m = 1; m < 64; m <<= 1) c += __shfl_xor(c, m);
    if (lane == 0) red[w] = c;
  }
  __syncthreads();
  const int n_in = red[0] + red[1] + red[2] + red[3];
  const int need = TK - n_in;
  int* sb = selg + (size_t)gid * TK;
  if (tid == 0) runS = 0;
  __syncthreads();
  for (int ck = 0; ck < 12; ck++){
    int j = ck*256 + tid;
    bool f = (cu[j] > thr_hi);
    unsigned long long bal = __ballot(f);
    int wpre = __popcll(bal & ((1ull << lane) - 1ull));
    int wtot = __popcll(bal);
    if (lane == 0) red[w] = wtot;
    __syncthreads();
    int woff = 0;
    for (int x = 0; x < w; x++) woff += red[x];
    int base = runS;
    if (f) sb[base + woff + wpre] = j;
    __syncthreads();
    if (tid == 0) runS = base + red[0] + red[1] + red[2] + red[3];
    __syncthreads();
  }
  if (tid == 0) runS = 0;
  __syncthreads();
  for (int ck = 0; ck < 12; ck++){
    int j = ck*256 + tid;
    bool f = (!(cu[j] > thr_hi)) && (cu[j] >= thr_lo);
    unsigned long long bal = __ballot(f);
    int wpre = __popcll(bal & ((1ull << lane) - 1ull));
    int wtot = __popcll(bal);
    if (lane == 0) red[w] = wtot;
    __syncthreads();
    int woff = 0;
    for (int x = 0; x < w; x++) woff += red[x];
    int base = runS;
    int pos = base + woff + wpre;
    if (f && pos < MAXC) cidx[pos] = j;
    __syncthreads();
    if (tid == 0) runS = base + red[0] + red[1] + red[2] + red[3];
    __syncthreads();
  }
  int ccnt = runS < MAXC ? runS : MAXC;
  __syncthreads();
  const int row = g*192 + (tid < 192 ? tid : 0);
  const float* qp = qg + ((size_t)h*N + row)*DH;
  const double Zrow = Zd[h*N + row];
  for (int c = 0; c < ccnt; c++){
    double t = 0.0;
    if (tid < 192){
      const float* kp = kg + ((size_t)h*N + cidx[c])*DH;
      double a0 = 0.0, a1 = 0.0, a2 = 0.0, a3 = 0.0;
#pragma unroll 4
      for (int d = 0; d < DH; d += 4){
        a0 = fma((double)qp[d],   (double)kp[d],   a0);
        a1 = fma((double)qp[d+1], (double)kp[d+1], a1);
        a2 = fma((double)qp[d+2], (double)kp[d+2], a2);
        a3 = fma((double)qp[d+3], (double)kp[d+3], a3);
      }
      double z = ((a0 + a1) + (a2 + a3)) * 0.08838834764831845;
      t = exp(z) / Zrow;
    }
    rbuf[tid] = t;
    __syncthreads();
#pragma unroll
    for (int s = 128; s > 0; s >>= 1){
      if (tid < s) rbuf[tid] += rbuf[tid + s];
      __syncthreads();
    }
    if (tid == 0) cval[c] = rbuf[0];
    __syncthreads();
  }
  if (tid < ccnt){
    double my = cval[tid];
    int myi = cidx[tid];
    int rank = 0;
    for (int u = 0; u < ccnt; u++){
      double cu_ = cval[u];
      if (cu_ > my || (cu_ == my && cidx[u] < myi)) rank++;
    }
    if (rank < need) sb[n_in + rank] = myi;
  }
}

// ------- kernel D: o_S, rho over selected keys; out -= o_S/rho (in place) -------
template<int DMA>
__global__ __launch_bounds__(256, 3) void kD(const float* __restrict__ qg,
                                             const float* __restrict__ kg,
                                             const float* __restrict__ vg,
                                             const double* __restrict__ Zg,
                                             const int* __restrict__ selg,
                                             const unsigned short* __restrict__ khig,
                                             const unsigned short* __restrict__ klog,
                                             float* __restrict__ outg){
  __shared__ alignas(16) char khi[2][8192];
  __shared__ alignas(16) char klo[2][8192];
  __shared__ alignas(16) char vts[10240];
  __shared__ alignas(16) char pls[4][1280];
  __shared__ int sell[TK];
  int h, ch; mapHC(blockIdx.x, h, ch);
  const int tid = threadIdx.x, w = tid >> 6, lane = tid & 63;
  const int l15 = lane & 15, l4 = lane >> 4;
  const int R = ch * 64;
  const int g = ch / 3;
  const float* qhead = qg + (size_t)h*N*DH;
  const float* khead = kg + (size_t)h*N*DH;
  const float* vhead = vg + (size_t)h*N*DH;
  const int* sb = selg + (size_t)(h*16 + g) * TK;
  for (int i = tid; i < TK; i += 256) sell[i] = sb[i];
  uint4 qh[4], ql[4];
  load_qfrags2(qhead, R, w, lane, qh, ql);
  float rz[4];
#pragma unroll
  for (int r = 0; r < 4; r++)
    rz[r] = (float)(1.0 / Zg[h*N + R + w*16 + l4*4 + r]);
  f32x4 oac[8];
#pragma unroll
  for (int i = 0; i < 8; i++) oac[i] = f4zero();
  float rh[4] = {0.f,0.f,0.f,0.f};

  int p0g = 0, p1g = 0, sl0 = 0, sl1 = 0;
  if (DMA){
    int g0 = w*128 + lane, g1 = g0 + 64;
    p0g = g0 >> 4; sl0 = (g0 & 15) ^ (p0g & 7);
    p1g = g1 >> 4; sl1 = (g1 & 15) ^ (p1g & 7);
  }
  const int wofs = w*2048;
  const int jst = tid >> 3, dblk = tid & 7;
  const int jv2 = (tid & 15)*2, dv8 = (tid >> 4)*8;
  __syncthreads();                         // sell visible
  // prologue: stage tile 0
  if (DMA){
    size_t b0 = ((size_t)h*N + sell[p0g])*DH + sl0*8;
    size_t b1 = ((size_t)h*N + sell[p1g])*DH + sl1*8;
    GLD16(khig + b0, khi[0] + wofs);  GLD16(khig + b1, khi[0] + wofs + 1024);
    GLD16(klog + b0, klo[0] + wofs);  GLD16(klog + b1, klo[0] + wofs + 1024);
  } else {
    float4 k0r[4];
    ldK16(khead + (size_t)sell[jst]*DH + dblk*16, k0r);
    wrK16(k0r, khi[0], klo[0], jst, dblk);
  }
  {
    V16 v0 = load_v(vhead + (size_t)sell[jv2]*DH + dv8,
                    vhead + (size_t)sell[jv2+1]*DH + dv8);
    write_v(v0, vts, jv2, dv8);
  }
  __syncthreads();
  float4 kr[4];
  V16 vr;
  for (int st = 0; st < 28; st++){
    int cur = st & 1;
    if (st < 27){
      if (DMA){
        size_t b0 = ((size_t)h*N + sell[(st+1)*32 + p0g])*DH + sl0*8;
        size_t b1 = ((size_t)h*N + sell[(st+1)*32 + p1g])*DH + sl1*8;
        GLD16(khig + b0, khi[cur^1] + wofs);  GLD16(khig + b1, khi[cur^1] + wofs + 1024);
        GLD16(klog + b0, klo[cur^1] + wofs);  GLD16(klog + b1, klo[cur^1] + wofs + 1024);
      } else {
        ldK16(khead + (size_t)sell[(st+1)*32 + jst]*DH + dblk*16, kr);
      }
      vr = load_v(vhead + (size_t)sell[(st+1)*32 + jv2]*DH + dv8,
                  vhead + (size_t)sell[(st+1)*32 + jv2 + 1]*DH + dv8);
    }
    f32x4 zac[2];
    zcompute3(khi[cur], klo[cur], qh, ql, lane, zac);
    float pn[2][4];
#pragma unroll
    for (int ct = 0; ct < 2; ct++)
#pragma unroll
      for (int r = 0; r < 4; r++){
        pn[ct][r] = __expf(zac[ct][r]) * rz[r];
        rh[r] += pn[ct][r];
      }
    pv_step(pn, pls[w], vts, oac, l15, l4);
    __syncthreads();                       // barrier1
    if (st < 27){
      write_v(vr, vts, jv2, dv8);
      if (!DMA) wrK16(kr, khi[cur^1], klo[cur^1], jst, dblk);
    }
    __syncthreads();                       // barrier2
  }
#pragma unroll
  for (int m = 1; m < 16; m <<= 1)
#pragma unroll
    for (int r = 0; r < 4; r++)
      rh[r] += __shfl_xor(rh[r], m);
  float ri[4];
#pragma unroll
  for (int r = 0; r < 4; r++) ri[r] = 1.0f / rh[r];
#pragma unroll
  for (int vt = 0; vt < 8; vt++)
#pragma unroll
    for (int r = 0; r < 4; r++){
      size_t idx = ((size_t)h*N + R + w*16 + l4*4 + r)*DH + vt*16 + l15;
      outg[idx] = outg[idx] - oac[vt][r]*ri[r];
    }
}

extern "C" void kernel_launch(void* const* d_in, const int* in_sizes, int n_in,
                              void* d_out, int out_size, void* d_ws, size_t ws_size,
                              hipStream_t stream){
  (void)in_sizes; (void)n_in; (void)out_size;
  const float* q = (const float*)d_in[0];
  const float* k = (const float*)d_in[1];
  const float* v = (const float*)d_in[2];
  float* out = (float*)d_out;
  const size_t KELEMS = (size_t)H*N*DH;            // 9,437,184
  const size_t KBYTES = KELEMS*2;                  // 18,874,368
  const size_t ZB = (size_t)H*N*8;                 // 589,824 (f64)
  const size_t CPB = (size_t)1152*3072*4;          // 14,155,776
  const size_t SELB = (size_t)384*TK*4;            // 1,376,256
  const bool dma = ws_size >= 2*KBYTES + ZB + CPB + SELB;   // ~51.4 MB
  char* wsb = (char*)d_ws;
  unsigned short *khig = nullptr, *klog = nullptr;
  double* Z; float* cpart; int* sel;
  if (dma){
    khig = (unsigned short*)wsb;
    klog = (unsigned short*)(wsb + KBYTES);
    Z = (double*)(wsb + 2*KBYTES);
    cpart = (float*)(wsb + 2*KBYTES + ZB);
    sel = (int*)(wsb + 2*KBYTES + ZB + CPB);
  } else {
    Z = (double*)wsb;
    cpart = (float*)(wsb + ZB);
    sel = (int*)(wsb + ZB + CPB);
  }
  if (dma){
    kS<<<dim3(4608), dim3(256), 0, stream>>>(k, khig, klog);
    kAB<1><<<dim3(1152), dim3(256), 0, stream>>>(q, k, v, khig, klog, Z, cpart, out);
    kC<<<dim3(384), dim3(256), 0, stream>>>(cpart, Z, q, k, sel);
    kD<1><<<dim3(1152), dim3(256), 0, stream>>>(q, k, v, Z, sel, khig, klog, out);
  } else {
    kAB<0><<<dim3(1152), dim3(256), 0, stream>>>(q, k, v, khig, klog, Z, cpart, out);
    kC<<<dim3(384), dim3(256), 0, stream>>>(cpart, Z, q, k, sel);
    kD<0><<<dim3(1152), dim3(256), 0, stream>>>(q, k, v, Z, sel, khig, klog, out);
  }
}